// Round 5
// baseline (268.565 us; speedup 1.0000x reference)
//
#include <hip/hip_runtime.h>

// R10: swapped-operand attention + barrier-free projections.
//  - QK^T computed transposed (A=K, B=Q): softmax column is lane-local -> max/sum are
//    in-reg + 2 shfls (was 16), m/l scalar, P^T scatter = 4 packed b64 writes (was 16 b16),
//    PV swapped (A=V, B=P^T), epilogue = direct bf16x4 stores (no LDS, no barriers).
//  - Q-proj barrier-free: Q^T = mfma(A=Wq-frag direct-global, B=z-frag direct-global),
//    same-wave sigma-swizzled LDS round-trip into qt. No prologue barriers at all.
//  - proj v2 (o-proj): A-frags direct from global with depth-1 prefetch; sB staged once;
//    ZERO barriers in the kb loop. LDS 40960 -> 24576.
//  - Keeps: reg K/V prefetch staging (2 barriers/chunk), defer-max THR=8 (scalar),
//    exp2-domain, sigma LDS swizzles, fused pre (zt+kv).

typedef float  f32x4  __attribute__((ext_vector_type(4)));
typedef __bf16 bf16;
typedef __bf16 bf16x4 __attribute__((ext_vector_type(4)));
typedef __bf16 bf16x8 __attribute__((ext_vector_type(8)));

#define B_   16
#define D_   192
#define T_   4096
#define BANK 1000
#define SP   1024
#define DK   96
#define SCALE 0.10206207261596577f   // 1/sqrt(96)
#define LOG2E 1.4426950408889634f

// ---------------- fused pre-work: zt (y<16) | kv (y>=16) ----------------
__global__ __launch_bounds__(256) void pre_kernel(
    const float* __restrict__ z, bf16* __restrict__ zT,
    const float* __restrict__ mb,
    const float* __restrict__ Wk, const float* __restrict__ bk,
    const float* __restrict__ Wv, const float* __restrict__ bv,
    bf16* __restrict__ ktg, bf16* __restrict__ vtg) {
  __shared__ __align__(16) bf16 sT[64 * 200];
  const int tid = threadIdx.x;
  if (blockIdx.y < 16) {
    // z transpose: z f32 [b][c][t] -> zT bf16 [b][t][c]
    const int t0 = blockIdx.x * 64, b = blockIdx.y;
#pragma unroll
    for (int it = 0; it < 48; ++it) {        // 192c x 64t, coalesced along t
      int e = tid + 256 * it;
      int c = e >> 6, tl = e & 63;
      sT[tl * 200 + c] = (bf16)z[((size_t)b * D_ + c) * T_ + t0 + tl];
    }
    __syncthreads();
#pragma unroll
    for (int it = 0; it < 6; ++it) {         // 1536 granules of 8 bf16
      int g = tid + 256 * it;
      int tl = g / 24, c8 = (g % 24) * 8;
      bf16x8 v = *(const bf16x8*)&sT[tl * 200 + c8];
      *(bf16x8*)&zT[((size_t)b * T_ + t0 + tl) * D_ + c8] = v;
    }
  } else {
    // K/V projection: ktg [h][1024 s][96 i], vtg [h][96 i][1024 s]
    int idx = (blockIdx.y - 16) * 64 + blockIdx.x;   // 0..767
    int s = (idx & 3) * 256 + tid;
    int o = idx >> 2;
    int h = o / DK, i = o % DK;
    float ak = 0.f, av = 0.f;
    if (s < BANK) {
      ak = bk[o]; av = bv[o];
      for (int c = 0; c < D_; ++c) {
        float m = mb[c * BANK + s];
        ak += Wk[o * D_ + c] * m;
        av += Wv[o * D_ + c] * m;
      }
    }
    ktg[(size_t)(h * SP + s) * DK + i] = (bf16)ak;
    vtg[(size_t)(h * DK + i) * SP + s] = (bf16)av;
  }
}

// ---------------- MFMA projection v2: Y[b][o][t] = (W · X + bias) * outscale ----------------
// XT bf16 [b][t][192 c]; W f32 [o][c]; Y (f32 or bf16) [b][o][t].
// A-frags direct from global with depth-1 prefetch; sB staged once; no loop barriers.
template <typename OT>
__global__ __launch_bounds__(256) void proj_kernel(
    const bf16* __restrict__ XT, const float* __restrict__ W,
    const float* __restrict__ bias, OT* __restrict__ Y, float outscale) {
  __shared__ __align__(16) char smem[24576];
  bf16* sB = (bf16*)smem;                    // [6 kb][4 nt][64 lane][8] = 24576 B
  float* sE = (float*)smem;                  // epilogue overlay: 4 waves x [16][68] f32

  const int tid = threadIdx.x;
  const int t0 = blockIdx.x * 256, o0 = blockIdx.y * 64, b = blockIdx.z;
  const int lane = tid & 63, wv = tid >> 6;
  const int quad = lane >> 4, l15 = lane & 15;

  // A-frag direct-global pointers (per m-tile); issue kb=0 loads immediately
  const bf16* ap[4];
#pragma unroll
  for (int m = 0; m < 4; ++m)
    ap[m] = &XT[((size_t)b * T_ + t0 + (wv * 4 + m) * 16 + l15) * D_ + quad * 8];
  bf16x8 acur[4];
#pragma unroll
  for (int m = 0; m < 4; ++m) acur[m] = *(const bf16x8*)ap[m];

  // stage W once (64o x 192c) as packed B-frags, f32 -> bf16
#pragma unroll
  for (int r = 0; r < 6; ++r) {
    int g = tid + 256 * r;                   // [kb][nt][lane]
    int kb = g >> 8, nt = (g >> 6) & 3, qd = (g >> 4) & 3, l5 = g & 15;
    const float* wp = &W[(o0 + nt * 16 + l5) * D_ + kb * 32 + qd * 8];
    f32x4 wa = *(const f32x4*)wp, wb = *(const f32x4*)(wp + 4);
    bf16x8 pk;
#pragma unroll
    for (int u = 0; u < 4; ++u) { pk[u] = (bf16)wa[u]; pk[4 + u] = (bf16)wb[u]; }
    *(bf16x8*)&sB[(size_t)g * 8] = pk;
  }

  f32x4 acc[4][4];
#pragma unroll
  for (int m = 0; m < 4; ++m)
#pragma unroll
    for (int n = 0; n < 4; ++n) acc[m][n] = (f32x4){0.f, 0.f, 0.f, 0.f};

  __syncthreads();                           // sB ready (only loop-entry barrier)
  for (int kb = 0; kb < 6; ++kb) {
    bf16x8 anext[4];
    if (kb < 5) {
#pragma unroll
      for (int m = 0; m < 4; ++m)
        anext[m] = *(const bf16x8*)(ap[m] + (kb + 1) * 32);
    }
    bf16x8 bf[4];
#pragma unroll
    for (int n = 0; n < 4; ++n)
      bf[n] = *(const bf16x8*)&sB[(size_t)((kb * 4 + n) * 64 + lane) * 8];
#pragma unroll
    for (int m = 0; m < 4; ++m)
#pragma unroll
      for (int n = 0; n < 4; ++n)
        acc[m][n] = __builtin_amdgcn_mfma_f32_16x16x32_bf16(acur[m], bf[n], acc[m][n], 0, 0, 0);
    if (kb < 5) {
#pragma unroll
      for (int m = 0; m < 4; ++m) acur[m] = anext[m];
    }
  }
  __syncthreads();                           // before epilogue overlay

  float bs[4];
#pragma unroll
  for (int n = 0; n < 4; ++n) bs[n] = bias[o0 + n * 16 + l15];
  float* se = sE + wv * 1088;                // [16 t][68]
#pragma unroll
  for (int m = 0; m < 4; ++m) {
#pragma unroll
    for (int n = 0; n < 4; ++n)
#pragma unroll
      for (int r = 0; r < 4; ++r)
        se[(quad * 4 + r) * 68 + n * 16 + l15] = (acc[m][n][r] + bs[n]) * outscale;
#pragma unroll
    for (int oo = 0; oo < 16; ++oo) {        // same-wave DS in-order: no barrier
      int ol = oo * 4 + quad;
      Y[((size_t)b * D_ + o0 + ol) * T_ + t0 + wv * 64 + m * 16 + l15] =
          (OT)se[l15 * 68 + ol];
    }
  }
}

// ---------------- swapped-operand fused Q-proj + flash attention ----------------
// Block = (b, h, 128 t); 8 waves x 16 t. Chunk = 64 s.
// S^T = mfma(K, Q): lane owns one t-column -> in-reg softmax (2 shfls), scalar m/l.
// PV swapped: O^T = mfma(V, P^T). LDS 32768: kt 12288 | vt 12288 | sP 8192.
__global__ __launch_bounds__(512) void attn_kernel(
    const bf16* __restrict__ zT, const float* __restrict__ Wq,
    const float* __restrict__ bq, const bf16* __restrict__ ktg,
    const bf16* __restrict__ vtg, bf16* __restrict__ owsT) {
  __shared__ __align__(16) char smem[32768];
  bf16* kt = (bf16*)smem;                    // [3 kb][4 n][64][8] = 12288
  bf16* vt = (bf16*)(smem + 12288);          // [2 kb][6 n][64][8] = 12288
  bf16* sP = (bf16*)(smem + 24576);          // [8 wv][64][8]      =  8192
  bf16* qt = (bf16*)smem;                    // prologue overlay (24576)

  const int tid = threadIdx.x;
  const int t0 = blockIdx.x * 128, h = blockIdx.y, b = blockIdx.z;
  const int lane = tid & 63, wv = tid >> 6;
  const int quad = lane >> 4, l15 = lane & 15;

  // K/V staging pointers + chunk-0 prefetch (issued first: hides under Q-proj)
  const bf16* kb_g = ktg + (size_t)h * SP * DK;
  const bf16* vb_g = vtg + (size_t)h * DK * SP;
  const bf16* sp_ptr[3];
  int sp_str[3];
#pragma unroll
  for (int r = 0; r < 3; ++r) {
    int g = tid + 512 * r;
    if (g < 768) {                           // K granule
      int kb = g >> 8, n = (g >> 6) & 3, qd = (g >> 4) & 3, l5 = g & 15;
      sp_ptr[r] = kb_g + (size_t)(n * 16 + l5) * DK + kb * 32 + qd * 8;
      sp_str[r] = 64 * DK;
    } else {                                 // V granule
      int gv = g - 768, blk = gv >> 6;
      int kbv = blk / 6, n = blk % 6, qd = (gv >> 4) & 3, l5 = gv & 15;
      sp_ptr[r] = vb_g + (size_t)(n * 16 + l5) * SP + kbv * 32 + qd * 8;
      sp_str[r] = 64;
    }
  }
  bf16x8 kreg[3];
#pragma unroll
  for (int r = 0; r < 3; ++r) kreg[r] = *(const bf16x8*)sp_ptr[r];

  // ======== barrier-free Q^T projection: Q^T = Wq · z  (A=Wq rows i, B=z cols t) ========
  f32x4 qacc[6];
#pragma unroll
  for (int n = 0; n < 6; ++n) qacc[n] = (f32x4){0.f, 0.f, 0.f, 0.f};
  const bf16*  zrow = &zT[((size_t)b * T_ + t0 + wv * 16 + l15) * D_ + quad * 8];
  const float* wrow = &Wq[(size_t)(h * DK + l15) * D_ + quad * 8];
  for (int kb = 0; kb < 6; ++kb) {
    bf16x8 zf = *(const bf16x8*)(zrow + kb * 32);
#pragma unroll
    for (int n = 0; n < 6; ++n) {
      const float* wp = wrow + (size_t)n * 16 * D_ + kb * 32;
      f32x4 wa = *(const f32x4*)wp, wb = *(const f32x4*)(wp + 4);
      bf16x8 wf;
#pragma unroll
      for (int u = 0; u < 4; ++u) { wf[u] = (bf16)wa[u]; wf[4 + u] = (bf16)wb[u]; }
      qacc[n] = __builtin_amdgcn_mfma_f32_16x16x32_bf16(wf, zf, qacc[n], 0, 0, 0);
    }
  }
  // scatter Q^T -> sigma-swizzled qt B-frags (same-wave b64 writes, no barrier)
#pragma unroll
  for (int n = 0; n < 6; ++n) {
    f32x4 bq4 = *(const f32x4*)&bq[h * DK + n * 16 + quad * 4];
    int g = ((n & 1) * 2 + (quad >> 1)) * 16 + l15;
    int gs = g ^ ((g >> 3) & 7);
    bf16x4 pk;
#pragma unroll
    for (int r = 0; r < 4; ++r)
      pk[r] = (bf16)((qacc[n][r] + bq4[r]) * (SCALE * LOG2E));
    *(bf16x4*)&qt[(size_t)(((n >> 1) * 8 + wv) * 64 + gs) * 8 + (quad & 1) * 4] = pk;
  }
  bf16x8 qf[3];                              // Q^T fragments (B-operand), same-wave read
#pragma unroll
  for (int kb = 0; kb < 3; ++kb)
    qf[kb] = *(const bf16x8*)&qt[(size_t)((kb * 8 + wv) * 64 + (lane ^ ((lane >> 3) & 7))) * 8];

  f32x4 oaccT[6];
#pragma unroll
  for (int n = 0; n < 6; ++n) oaccT[n] = (f32x4){0.f, 0.f, 0.f, 0.f};
  float m_run = -1e30f, l_run = 0.f;

  for (int ch = 0; ch < 16; ++ch) {
    __syncthreads();                         // (A) prev readers (first: qt reads) done
#pragma unroll
    for (int r = 0; r < 3; ++r)              // regs -> LDS, lane-linear (conflict-free)
      *(bf16x8*)(smem + (size_t)(tid + 512 * r) * 16) = kreg[r];
    __syncthreads();                         // (B) staged
    if (ch < 15) {                           // issue next chunk's loads under compute
#pragma unroll
      for (int r = 0; r < 3; ++r) {
        sp_ptr[r] += sp_str[r];
        kreg[r] = *(const bf16x8*)sp_ptr[r];
      }
    }

    // ---- S^T = K·Q^T: scT[n][r] = S[s = n*16+quad*4+r][t = wv*16+l15] ----
    f32x4 scT[4];
#pragma unroll
    for (int n = 0; n < 4; ++n) scT[n] = (f32x4){0.f, 0.f, 0.f, 0.f};
#pragma unroll
    for (int kb = 0; kb < 3; ++kb) {
#pragma unroll
      for (int n = 0; n < 4; ++n) {
        bf16x8 kf = *(const bf16x8*)&kt[(size_t)((kb * 4 + n) * 64 + lane) * 8];
        scT[n] = __builtin_amdgcn_mfma_f32_16x16x32_bf16(kf, qf[kb], scT[n], 0, 0, 0);
      }
    }
    if (ch == 15) {                          // mask s >= 1000 (s-local >= 40)
#pragma unroll
      for (int r = 0; r < 4; ++r) {
        scT[3][r] = -1e30f;
        if (quad >= 2) scT[2][r] = -1e30f;
      }
    }

    // ---- column softmax (t = l15): in-reg over 16, 2 shfls across quads ----
    float m0 = -1e30f;
#pragma unroll
    for (int n = 0; n < 4; ++n)
#pragma unroll
      for (int r = 0; r < 4; ++r) m0 = fmaxf(m0, scT[n][r]);
    m0 = fmaxf(m0, __shfl_xor(m0, 16, 64));
    m0 = fmaxf(m0, __shfl_xor(m0, 32, 64));
    if (!__all(m0 - m_run <= 8.f)) {         // defer-max (T13)
      float mn = fmaxf(m_run, m0);
      float al = exp2f(m_run - mn);
      m_run = mn;
      l_run *= al;
#pragma unroll
      for (int n = 0; n < 6; ++n)
#pragma unroll
        for (int r = 0; r < 4; ++r) oaccT[n][r] *= al;
    }
    float pr[4][4];
    float ls = 0.f;
#pragma unroll
    for (int n = 0; n < 4; ++n)
#pragma unroll
      for (int r = 0; r < 4; ++r) { pr[n][r] = exp2f(scT[n][r] - m_run); ls += pr[n][r]; }
    ls += __shfl_xor(ls, 16, 64);
    ls += __shfl_xor(ls, 32, 64);
    l_run += ls;

    // ---- P^T -> sP B-frags (packed b64, same-wave), PV: O^T += V·P^T ----
#pragma unroll
    for (int kb2 = 0; kb2 < 2; ++kb2) {
#pragma unroll
      for (int nh = 0; nh < 2; ++nh) {
        int n = kb2 * 2 + nh;
        int g = (nh * 2 + (quad >> 1)) * 16 + l15;
        int gs = g ^ ((g >> 3) & 7);
        bf16x4 pk = {(bf16)pr[n][0], (bf16)pr[n][1], (bf16)pr[n][2], (bf16)pr[n][3]};
        *(bf16x4*)&sP[(size_t)(wv * 64 + gs) * 8 + (quad & 1) * 4] = pk;
      }
      bf16x8 pa = *(const bf16x8*)&sP[(size_t)(wv * 64 + (lane ^ ((lane >> 3) & 7))) * 8];
#pragma unroll
      for (int n2 = 0; n2 < 6; ++n2) {
        bf16x8 vf = *(const bf16x8*)&vt[(size_t)((kb2 * 6 + n2) * 64 + lane) * 8];
        oaccT[n2] = __builtin_amdgcn_mfma_f32_16x16x32_bf16(vf, pa, oaccT[n2], 0, 0, 0);
      }
    }
  }

  // ---- epilogue: /l, direct bf16x4 global stores (no LDS, no barrier) ----
  float inv = 1.0f / l_run;
  bf16* orow = &owsT[((size_t)b * T_ + t0 + wv * 16 + l15) * D_ + h * DK + quad * 4];
#pragma unroll
  for (int n2 = 0; n2 < 6; ++n2) {
    bf16x4 pk = {(bf16)(oaccT[n2][0] * inv), (bf16)(oaccT[n2][1] * inv),
                 (bf16)(oaccT[n2][2] * inv), (bf16)(oaccT[n2][3] * inv)};
    *(bf16x4*)&orow[n2 * 16] = pk;
  }
}

extern "C" void kernel_launch(void* const* d_in, const int* in_sizes, int n_in,
                              void* d_out, int out_size, void* d_ws, size_t ws_size,
                              hipStream_t stream) {
  const float* z  = (const float*)d_in[0];
  const float* mb = (const float*)d_in[1];
  const float* Wq = (const float*)d_in[2];
  const float* bq = (const float*)d_in[3];
  const float* Wk = (const float*)d_in[4];
  const float* bk = (const float*)d_in[5];
  const float* Wv = (const float*)d_in[6];
  const float* bv = (const float*)d_in[7];
  const float* Wo = (const float*)d_in[8];
  const float* bo = (const float*)d_in[9];
  float* out = (float*)d_out;

  // ws: ktg | vtg | zT | owsT (all bf16)
  bf16* ktg  = (bf16*)d_ws;
  bf16* vtg  = ktg + 2 * SP * DK;
  bf16* zT   = vtg + 2 * DK * SP;
  bf16* owsT = zT + (size_t)B_ * T_ * D_;

  pre_kernel        <<<dim3(64, 28),          256, 0, stream>>>(z, zT, mb, Wk, bk, Wv, bv,
                                                                ktg, vtg);
  attn_kernel       <<<dim3(T_ / 128, 2, B_), 512, 0, stream>>>(zT, Wq, bq, ktg, vtg, owsT);
  proj_kernel<float><<<dim3(T_ / 256, 3, B_), 256, 0, stream>>>(owsT, Wo, bo, out, 1.0f);
}

// Round 6
// 257.168 us; speedup vs baseline: 1.0443x; 1.0443x over previous
//
#include <hip/hip_runtime.h>

// R11: fix R10's serial-chain regression, keep its structural wins.
//  - Softmax max/sum as depth-4 pairwise trees (ILP 8) + 2 cross-quad shfls.
//  - zT phase ELIMINATED: attn's swapped Q-proj reads z (f32 [b][c][t]) directly --
//    B-frag = 8 strided dword loads/lane (4x64B segments/instr), cvt in-reg.
//    pre_kernel -> kv-only. Saves 75 MB of traffic + one phase dependency.
//  - proj epilogue: f32x4 stores (4 instr/m-tile instead of 64 scalar).
//  - Keeps: swapped S^T/PV MFMA, barrier-free Q-proj + direct epilogue stores,
//    packed b64 P^T scatter, sigma swizzles, reg K/V prefetch (2 barriers/chunk),
//    defer-max THR=8, exp2 domain.

typedef float  f32x4  __attribute__((ext_vector_type(4)));
typedef __bf16 bf16;
typedef __bf16 bf16x4 __attribute__((ext_vector_type(4)));
typedef __bf16 bf16x8 __attribute__((ext_vector_type(8)));

#define B_   16
#define D_   192
#define T_   4096
#define BANK 1000
#define SP   1024
#define DK   96
#define SCALE 0.10206207261596577f   // 1/sqrt(96)
#define LOG2E 1.4426950408889634f

// ---------------- K/V projection (tiny) ----------------
// ktg: [h][1024 s][96 i]   vtg: [h][96 i][1024 s]
__global__ __launch_bounds__(256) void kv_kernel(
    const float* __restrict__ mb, const float* __restrict__ Wk, const float* __restrict__ bk,
    const float* __restrict__ Wv, const float* __restrict__ bv,
    bf16* __restrict__ ktg, bf16* __restrict__ vtg) {
  int s = blockIdx.x * 256 + threadIdx.x;
  int o = blockIdx.y;
  int h = o / DK, i = o % DK;
  float ak = 0.f, av = 0.f;
  if (s < BANK) {
    ak = bk[o]; av = bv[o];
    for (int c = 0; c < D_; ++c) {
      float m = mb[c * BANK + s];
      ak += Wk[o * D_ + c] * m;
      av += Wv[o * D_ + c] * m;
    }
  }
  ktg[(size_t)(h * SP + s) * DK + i] = (bf16)ak;
  vtg[(size_t)(h * DK + i) * SP + s] = (bf16)av;
}

// ---------------- MFMA o-projection: out[b][o][t] = Wo · att + bo ----------------
// XT bf16 [b][t][192 c]; W f32 [o][c]; Y f32 [b][o][t].
// A-frags direct from global with depth-1 prefetch; sB staged once; no loop barriers.
__global__ __launch_bounds__(256) void proj_kernel(
    const bf16* __restrict__ XT, const float* __restrict__ W,
    const float* __restrict__ bias, float* __restrict__ Y) {
  __shared__ __align__(16) char smem[24576];
  bf16* sB = (bf16*)smem;                    // [6 kb][4 nt][64 lane][8] = 24576 B
  float* sE = (float*)smem;                  // epilogue overlay: 4 waves x [16][68] f32

  const int tid = threadIdx.x;
  const int t0 = blockIdx.x * 256, o0 = blockIdx.y * 64, b = blockIdx.z;
  const int lane = tid & 63, wv = tid >> 6;
  const int quad = lane >> 4, l15 = lane & 15;

  // A-frag direct-global pointers (per m-tile); issue kb=0 loads immediately
  const bf16* ap[4];
#pragma unroll
  for (int m = 0; m < 4; ++m)
    ap[m] = &XT[((size_t)b * T_ + t0 + (wv * 4 + m) * 16 + l15) * D_ + quad * 8];
  bf16x8 acur[4];
#pragma unroll
  for (int m = 0; m < 4; ++m) acur[m] = *(const bf16x8*)ap[m];

  // stage W once (64o x 192c) as packed B-frags, f32 -> bf16
#pragma unroll
  for (int r = 0; r < 6; ++r) {
    int g = tid + 256 * r;                   // [kb][nt][lane]
    int kb = g >> 8, nt = (g >> 6) & 3, qd = (g >> 4) & 3, l5 = g & 15;
    const float* wp = &W[(o0 + nt * 16 + l5) * D_ + kb * 32 + qd * 8];
    f32x4 wa = *(const f32x4*)wp, wb = *(const f32x4*)(wp + 4);
    bf16x8 pk;
#pragma unroll
    for (int u = 0; u < 4; ++u) { pk[u] = (bf16)wa[u]; pk[4 + u] = (bf16)wb[u]; }
    *(bf16x8*)&sB[(size_t)g * 8] = pk;
  }

  f32x4 acc[4][4];
#pragma unroll
  for (int m = 0; m < 4; ++m)
#pragma unroll
    for (int n = 0; n < 4; ++n) acc[m][n] = (f32x4){0.f, 0.f, 0.f, 0.f};

  __syncthreads();                           // sB ready (only loop-entry barrier)
  for (int kb = 0; kb < 6; ++kb) {
    bf16x8 anext[4];
    if (kb < 5) {
#pragma unroll
      for (int m = 0; m < 4; ++m)
        anext[m] = *(const bf16x8*)(ap[m] + (kb + 1) * 32);
    }
    bf16x8 bf[4];
#pragma unroll
    for (int n = 0; n < 4; ++n)
      bf[n] = *(const bf16x8*)&sB[(size_t)((kb * 4 + n) * 64 + lane) * 8];
#pragma unroll
    for (int m = 0; m < 4; ++m)
#pragma unroll
      for (int n = 0; n < 4; ++n)
        acc[m][n] = __builtin_amdgcn_mfma_f32_16x16x32_bf16(acur[m], bf[n], acc[m][n], 0, 0, 0);
    if (kb < 5) {
#pragma unroll
      for (int m = 0; m < 4; ++m) acur[m] = anext[m];
    }
  }
  __syncthreads();                           // before epilogue overlay

  float bs[4];
#pragma unroll
  for (int n = 0; n < 4; ++n) bs[n] = bias[o0 + n * 16 + l15];
  float* se = sE + wv * 1088;                // [16 t][68 o]
#pragma unroll
  for (int m = 0; m < 4; ++m) {
#pragma unroll
    for (int n = 0; n < 4; ++n)
#pragma unroll
      for (int r = 0; r < 4; ++r)
        se[(quad * 4 + r) * 68 + n * 16 + l15] = acc[m][n][r] + bs[n];
    // same-wave DS in-order: no barrier. f32x4 stores: 4 t per lane.
#pragma unroll
    for (int p = 0; p < 4; ++p) {
      int o = p * 16 + (lane >> 2), tq = (lane & 3) * 4;
      f32x4 vv;
#pragma unroll
      for (int u = 0; u < 4; ++u) vv[u] = se[(tq + u) * 68 + o];
      *(f32x4*)&Y[((size_t)b * D_ + o0 + o) * T_ + t0 + wv * 64 + m * 16 + tq] = vv;
    }
  }
}

// ---------------- swapped-operand fused Q-proj + flash attention ----------------
// Block = (b, h, 128 t); 8 waves x 16 t. Chunk = 64 s.
// S^T = mfma(K, Q): lane owns one t-column; tree softmax (depth 4) + 2 shfls.
// PV swapped: O^T = mfma(V, P^T). LDS 32768: kt 12288 | vt 12288 | sP 8192.
__global__ __launch_bounds__(512) void attn_kernel(
    const float* __restrict__ z, const float* __restrict__ Wq,
    const float* __restrict__ bq, const bf16* __restrict__ ktg,
    const bf16* __restrict__ vtg, bf16* __restrict__ owsT) {
  __shared__ __align__(16) char smem[32768];
  bf16* kt = (bf16*)smem;                    // [3 kb][4 n][64][8] = 12288
  bf16* vt = (bf16*)(smem + 12288);          // [2 kb][6 n][64][8] = 12288
  bf16* sP = (bf16*)(smem + 24576);          // [8 wv][64][8]      =  8192
  bf16* qt = (bf16*)smem;                    // prologue overlay (24576)

  const int tid = threadIdx.x;
  const int t0 = blockIdx.x * 128, h = blockIdx.y, b = blockIdx.z;
  const int lane = tid & 63, wv = tid >> 6;
  const int quad = lane >> 4, l15 = lane & 15;

  // K/V staging pointers + chunk-0 prefetch (issued first: hides under Q-proj)
  const bf16* kb_g = ktg + (size_t)h * SP * DK;
  const bf16* vb_g = vtg + (size_t)h * DK * SP;
  const bf16* sp_ptr[3];
  int sp_str[3];
#pragma unroll
  for (int r = 0; r < 3; ++r) {
    int g = tid + 512 * r;
    if (g < 768) {                           // K granule
      int kb = g >> 8, n = (g >> 6) & 3, qd = (g >> 4) & 3, l5 = g & 15;
      sp_ptr[r] = kb_g + (size_t)(n * 16 + l5) * DK + kb * 32 + qd * 8;
      sp_str[r] = 64 * DK;
    } else {                                 // V granule
      int gv = g - 768, blk = gv >> 6;
      int kbv = blk / 6, n = blk % 6, qd = (gv >> 4) & 3, l5 = gv & 15;
      sp_ptr[r] = vb_g + (size_t)(n * 16 + l5) * SP + kbv * 32 + qd * 8;
      sp_str[r] = 64;
    }
  }
  bf16x8 kreg[3];
#pragma unroll
  for (int r = 0; r < 3; ++r) kreg[r] = *(const bf16x8*)sp_ptr[r];

  // ======== barrier-free Q^T projection, z read DIRECT (f32 [b][c][t]) ========
  // B-frag zf[kb]: lane (quad,l15) holds z[b][kb*32 + quad*8 + j][t0 + wv*16 + l15].
  f32x4 qacc[6];
#pragma unroll
  for (int n = 0; n < 6; ++n) qacc[n] = (f32x4){0.f, 0.f, 0.f, 0.f};
  const float* zcol = &z[((size_t)b * D_ + quad * 8) * T_ + t0 + wv * 16 + l15];
  const float* wrow = &Wq[(size_t)(h * DK + l15) * D_ + quad * 8];
  for (int kb = 0; kb < 6; ++kb) {
    bf16x8 zf;
#pragma unroll
    for (int j = 0; j < 8; ++j)
      zf[j] = (bf16)zcol[(size_t)(kb * 32 + j) * T_];
#pragma unroll
    for (int n = 0; n < 6; ++n) {
      const float* wp = wrow + (size_t)n * 16 * D_ + kb * 32;
      f32x4 wa = *(const f32x4*)wp, wb = *(const f32x4*)(wp + 4);
      bf16x8 wf;
#pragma unroll
      for (int u = 0; u < 4; ++u) { wf[u] = (bf16)wa[u]; wf[4 + u] = (bf16)wb[u]; }
      qacc[n] = __builtin_amdgcn_mfma_f32_16x16x32_bf16(wf, zf, qacc[n], 0, 0, 0);
    }
  }
  // scatter Q^T -> sigma-swizzled qt B-frags (same-wave b64 writes, no barrier)
#pragma unroll
  for (int n = 0; n < 6; ++n) {
    f32x4 bq4 = *(const f32x4*)&bq[h * DK + n * 16 + quad * 4];
    int g = ((n & 1) * 2 + (quad >> 1)) * 16 + l15;
    int gs = g ^ ((g >> 3) & 7);
    bf16x4 pk;
#pragma unroll
    for (int r = 0; r < 4; ++r)
      pk[r] = (bf16)((qacc[n][r] + bq4[r]) * (SCALE * LOG2E));
    *(bf16x4*)&qt[(size_t)(((n >> 1) * 8 + wv) * 64 + gs) * 8 + (quad & 1) * 4] = pk;
  }
  bf16x8 qf[3];                              // Q^T fragments (B-operand), same-wave read
#pragma unroll
  for (int kb = 0; kb < 3; ++kb)
    qf[kb] = *(const bf16x8*)&qt[(size_t)((kb * 8 + wv) * 64 + (lane ^ ((lane >> 3) & 7))) * 8];

  f32x4 oaccT[6];
#pragma unroll
  for (int n = 0; n < 6; ++n) oaccT[n] = (f32x4){0.f, 0.f, 0.f, 0.f};
  float m_run = -1e30f, l_run = 0.f;

  for (int ch = 0; ch < 16; ++ch) {
    __syncthreads();                         // (A) prev readers (first: qt reads) done
#pragma unroll
    for (int r = 0; r < 3; ++r)              // regs -> LDS, lane-linear (conflict-free)
      *(bf16x8*)(smem + (size_t)(tid + 512 * r) * 16) = kreg[r];
    __syncthreads();                         // (B) staged
    if (ch < 15) {                           // issue next chunk's loads under compute
#pragma unroll
      for (int r = 0; r < 3; ++r) {
        sp_ptr[r] += sp_str[r];
        kreg[r] = *(const bf16x8*)sp_ptr[r];
      }
    }

    // ---- S^T = K·Q^T: scT[n][r] = S[s = n*16+quad*4+r][t = wv*16+l15] ----
    f32x4 scT[4];
#pragma unroll
    for (int n = 0; n < 4; ++n) scT[n] = (f32x4){0.f, 0.f, 0.f, 0.f};
#pragma unroll
    for (int kb = 0; kb < 3; ++kb) {
#pragma unroll
      for (int n = 0; n < 4; ++n) {
        bf16x8 kf = *(const bf16x8*)&kt[(size_t)((kb * 4 + n) * 64 + lane) * 8];
        scT[n] = __builtin_amdgcn_mfma_f32_16x16x32_bf16(kf, qf[kb], scT[n], 0, 0, 0);
      }
    }
    if (ch == 15) {                          // mask s >= 1000 (s-local >= 40)
#pragma unroll
      for (int r = 0; r < 4; ++r) {
        scT[3][r] = -1e30f;
        if (quad >= 2) scT[2][r] = -1e30f;
      }
    }

    // ---- column softmax: depth-4 trees (ILP 8) + 2 cross-quad shfls ----
    float m8[8];
#pragma unroll
    for (int u = 0; u < 8; ++u)
      m8[u] = fmaxf(scT[u >> 1][(u & 1) * 2], scT[u >> 1][(u & 1) * 2 + 1]);
    float m4a = fmaxf(m8[0], m8[1]), m4b = fmaxf(m8[2], m8[3]);
    float m4c = fmaxf(m8[4], m8[5]), m4d = fmaxf(m8[6], m8[7]);
    float m0 = fmaxf(fmaxf(m4a, m4b), fmaxf(m4c, m4d));
    m0 = fmaxf(m0, __shfl_xor(m0, 16, 64));
    m0 = fmaxf(m0, __shfl_xor(m0, 32, 64));
    if (!__all(m0 - m_run <= 8.f)) {         // defer-max (T13)
      float mn = fmaxf(m_run, m0);
      float al = exp2f(m_run - mn);
      m_run = mn;
      l_run *= al;
#pragma unroll
      for (int n = 0; n < 6; ++n)
#pragma unroll
        for (int r = 0; r < 4; ++r) oaccT[n][r] *= al;
    }
    float pr[4][4];
#pragma unroll
    for (int n = 0; n < 4; ++n)
#pragma unroll
      for (int r = 0; r < 4; ++r) pr[n][r] = exp2f(scT[n][r] - m_run);
    float s8[8];
#pragma unroll
    for (int u = 0; u < 8; ++u)
      s8[u] = pr[u >> 1][(u & 1) * 2] + pr[u >> 1][(u & 1) * 2 + 1];
    float s4a = s8[0] + s8[1], s4b = s8[2] + s8[3];
    float s4c = s8[4] + s8[5], s4d = s8[6] + s8[7];
    float ls = (s4a + s4b) + (s4c + s4d);
    ls += __shfl_xor(ls, 16, 64);
    ls += __shfl_xor(ls, 32, 64);
    l_run += ls;

    // ---- P^T -> sP B-frags (packed b64, same-wave), PV: O^T += V·P^T ----
#pragma unroll
    for (int kb2 = 0; kb2 < 2; ++kb2) {
#pragma unroll
      for (int nh = 0; nh < 2; ++nh) {
        int n = kb2 * 2 + nh;
        int g = (nh * 2 + (quad >> 1)) * 16 + l15;
        int gs = g ^ ((g >> 3) & 7);
        bf16x4 pk = {(bf16)pr[n][0], (bf16)pr[n][1], (bf16)pr[n][2], (bf16)pr[n][3]};
        *(bf16x4*)&sP[(size_t)(wv * 64 + gs) * 8 + (quad & 1) * 4] = pk;
      }
      bf16x8 pa = *(const bf16x8*)&sP[(size_t)(wv * 64 + (lane ^ ((lane >> 3) & 7))) * 8];
#pragma unroll
      for (int n2 = 0; n2 < 6; ++n2) {
        bf16x8 vf = *(const bf16x8*)&vt[(size_t)((kb2 * 6 + n2) * 64 + lane) * 8];
        oaccT[n2] = __builtin_amdgcn_mfma_f32_16x16x32_bf16(vf, pa, oaccT[n2], 0, 0, 0);
      }
    }
  }

  // ---- epilogue: /l, direct bf16x4 global stores (no LDS, no barrier) ----
  float inv = 1.0f / l_run;
  bf16* orow = &owsT[((size_t)b * T_ + t0 + wv * 16 + l15) * D_ + h * DK + quad * 4];
#pragma unroll
  for (int n2 = 0; n2 < 6; ++n2) {
    bf16x4 pk = {(bf16)(oaccT[n2][0] * inv), (bf16)(oaccT[n2][1] * inv),
                 (bf16)(oaccT[n2][2] * inv), (bf16)(oaccT[n2][3] * inv)};
    *(bf16x4*)&orow[n2 * 16] = pk;
  }
}

extern "C" void kernel_launch(void* const* d_in, const int* in_sizes, int n_in,
                              void* d_out, int out_size, void* d_ws, size_t ws_size,
                              hipStream_t stream) {
  const float* z  = (const float*)d_in[0];
  const float* mb = (const float*)d_in[1];
  const float* Wq = (const float*)d_in[2];
  const float* bq = (const float*)d_in[3];
  const float* Wk = (const float*)d_in[4];
  const float* bk = (const float*)d_in[5];
  const float* Wv = (const float*)d_in[6];
  const float* bv = (const float*)d_in[7];
  const float* Wo = (const float*)d_in[8];
  const float* bo = (const float*)d_in[9];
  float* out = (float*)d_out;

  // ws: ktg | vtg | owsT (all bf16)
  bf16* ktg  = (bf16*)d_ws;
  bf16* vtg  = ktg + 2 * SP * DK;
  bf16* owsT = vtg + 2 * DK * SP;

  kv_kernel  <<<dim3(SP / 256, D_),    256, 0, stream>>>(mb, Wk, bk, Wv, bv, ktg, vtg);
  attn_kernel<<<dim3(T_ / 128, 2, B_), 512, 0, stream>>>(z, Wq, bq, ktg, vtg, owsT);
  proj_kernel<<<dim3(T_ / 256, 3, B_), 256, 0, stream>>>(owsT, Wo, bo, out);
}

// Round 7
// 245.182 us; speedup vs baseline: 1.0954x; 1.0489x over previous
//
#include <hip/hip_runtime.h>

// R12: register tiling in attn — 2 t-tiles per wave (32 t), operand reuse.
//  - Every kt/vt LDS fragment read feeds 2 MFMAs (one per t-tile): reads/MFMA
//    0.58 vs 1.08. Two independent accumulator chains double per-wave ILP.
//  - Blocks: 256 thr / 4 waves / 128 t. LDS 40960: kt 12288 | vt 12288 | sP 16384
//    ([4 wv][2 t2][2 kb2][64][8]); qt prologue overlay 24576.
//  - Softmax per tile sequential (pr transient), P written for both kb2 halves
//    before PV so PV can reuse vf across tiles.
//  - Keeps: swapped S^T/PV, barrier-free fused Q-proj (z read direct), sigma
//    swizzles, reg K/V prefetch (2 barriers/chunk), defer-max THR=8, exp2 domain,
//    direct epilogue stores, kv-only pre kernel, barrier-free o-proj.

typedef float  f32x4  __attribute__((ext_vector_type(4)));
typedef __bf16 bf16;
typedef __bf16 bf16x4 __attribute__((ext_vector_type(4)));
typedef __bf16 bf16x8 __attribute__((ext_vector_type(8)));

#define B_   16
#define D_   192
#define T_   4096
#define BANK 1000
#define SP   1024
#define DK   96
#define SCALE 0.10206207261596577f   // 1/sqrt(96)
#define LOG2E 1.4426950408889634f

// ---------------- K/V projection (tiny) ----------------
// ktg: [h][1024 s][96 i]   vtg: [h][96 i][1024 s]
__global__ __launch_bounds__(256) void kv_kernel(
    const float* __restrict__ mb, const float* __restrict__ Wk, const float* __restrict__ bk,
    const float* __restrict__ Wv, const float* __restrict__ bv,
    bf16* __restrict__ ktg, bf16* __restrict__ vtg) {
  int s = blockIdx.x * 256 + threadIdx.x;
  int o = blockIdx.y;
  int h = o / DK, i = o % DK;
  float ak = 0.f, av = 0.f;
  if (s < BANK) {
    ak = bk[o]; av = bv[o];
    for (int c = 0; c < D_; ++c) {
      float m = mb[c * BANK + s];
      ak += Wk[o * D_ + c] * m;
      av += Wv[o * D_ + c] * m;
    }
  }
  ktg[(size_t)(h * SP + s) * DK + i] = (bf16)ak;
  vtg[(size_t)(h * DK + i) * SP + s] = (bf16)av;
}

// ---------------- MFMA o-projection: out[b][o][t] = Wo · att + bo ----------------
__global__ __launch_bounds__(256) void proj_kernel(
    const bf16* __restrict__ XT, const float* __restrict__ W,
    const float* __restrict__ bias, float* __restrict__ Y) {
  __shared__ __align__(16) char smem[24576];
  bf16* sB = (bf16*)smem;                    // [6 kb][4 nt][64 lane][8] = 24576 B
  float* sE = (float*)smem;                  // epilogue overlay: 4 waves x [16][68] f32

  const int tid = threadIdx.x;
  const int t0 = blockIdx.x * 256, o0 = blockIdx.y * 64, b = blockIdx.z;
  const int lane = tid & 63, wv = tid >> 6;
  const int quad = lane >> 4, l15 = lane & 15;

  const bf16* ap[4];
#pragma unroll
  for (int m = 0; m < 4; ++m)
    ap[m] = &XT[((size_t)b * T_ + t0 + (wv * 4 + m) * 16 + l15) * D_ + quad * 8];
  bf16x8 acur[4];
#pragma unroll
  for (int m = 0; m < 4; ++m) acur[m] = *(const bf16x8*)ap[m];

#pragma unroll
  for (int r = 0; r < 6; ++r) {
    int g = tid + 256 * r;                   // [kb][nt][lane]
    int kb = g >> 8, nt = (g >> 6) & 3, qd = (g >> 4) & 3, l5 = g & 15;
    const float* wp = &W[(o0 + nt * 16 + l5) * D_ + kb * 32 + qd * 8];
    f32x4 wa = *(const f32x4*)wp, wb = *(const f32x4*)(wp + 4);
    bf16x8 pk;
#pragma unroll
    for (int u = 0; u < 4; ++u) { pk[u] = (bf16)wa[u]; pk[4 + u] = (bf16)wb[u]; }
    *(bf16x8*)&sB[(size_t)g * 8] = pk;
  }

  f32x4 acc[4][4];
#pragma unroll
  for (int m = 0; m < 4; ++m)
#pragma unroll
    for (int n = 0; n < 4; ++n) acc[m][n] = (f32x4){0.f, 0.f, 0.f, 0.f};

  __syncthreads();                           // sB ready (only loop-entry barrier)
  for (int kb = 0; kb < 6; ++kb) {
    bf16x8 anext[4];
    if (kb < 5) {
#pragma unroll
      for (int m = 0; m < 4; ++m)
        anext[m] = *(const bf16x8*)(ap[m] + (kb + 1) * 32);
    }
    bf16x8 bf[4];
#pragma unroll
    for (int n = 0; n < 4; ++n)
      bf[n] = *(const bf16x8*)&sB[(size_t)((kb * 4 + n) * 64 + lane) * 8];
#pragma unroll
    for (int m = 0; m < 4; ++m)
#pragma unroll
      for (int n = 0; n < 4; ++n)
        acc[m][n] = __builtin_amdgcn_mfma_f32_16x16x32_bf16(acur[m], bf[n], acc[m][n], 0, 0, 0);
    if (kb < 5) {
#pragma unroll
      for (int m = 0; m < 4; ++m) acur[m] = anext[m];
    }
  }
  __syncthreads();                           // before epilogue overlay

  float bs[4];
#pragma unroll
  for (int n = 0; n < 4; ++n) bs[n] = bias[o0 + n * 16 + l15];
  float* se = sE + wv * 1088;                // [16 t][68 o]
#pragma unroll
  for (int m = 0; m < 4; ++m) {
#pragma unroll
    for (int n = 0; n < 4; ++n)
#pragma unroll
      for (int r = 0; r < 4; ++r)
        se[(quad * 4 + r) * 68 + n * 16 + l15] = acc[m][n][r] + bs[n];
    // same-wave DS in-order: no barrier. f32x4 stores: 4 t per lane.
#pragma unroll
    for (int p = 0; p < 4; ++p) {
      int o = p * 16 + (lane >> 2), tq = (lane & 3) * 4;
      f32x4 vv;
#pragma unroll
      for (int u = 0; u < 4; ++u) vv[u] = se[(tq + u) * 68 + o];
      *(f32x4*)&Y[((size_t)b * D_ + o0 + o) * T_ + t0 + wv * 64 + m * 16 + tq] = vv;
    }
  }
}

// ---------------- swapped-operand fused Q-proj + flash attention, 2 t-tiles/wave ----------------
// Block = (b, h, 128 t); 4 waves x 32 t (2 tiles of 16). Chunk = 64 s.
// S^T = mfma(K, Q[t2]); PV: O^T[t2] = mfma(V, P^T[t2]) -- kt/vt frags reused x2.
__global__ __launch_bounds__(256) void attn_kernel(
    const float* __restrict__ z, const float* __restrict__ Wq,
    const float* __restrict__ bq, const bf16* __restrict__ ktg,
    const bf16* __restrict__ vtg, bf16* __restrict__ owsT) {
  __shared__ __align__(16) char smem[40960];
  bf16* kt = (bf16*)smem;                    // [3 kb][4 n][64][8]      = 12288
  bf16* vt = (bf16*)(smem + 12288);          // [2 kb][6 n][64][8]      = 12288
  bf16* sP = (bf16*)(smem + 24576);          // [4 wv][2 t2][2 kb2][64][8] = 16384
  bf16* qt = (bf16*)smem;                    // prologue overlay (24576)

  const int tid = threadIdx.x;
  const int t0 = blockIdx.x * 128, h = blockIdx.y, b = blockIdx.z;
  const int lane = tid & 63, wv = tid >> 6;
  const int quad = lane >> 4, l15 = lane & 15;

  // K/V staging pointers + chunk-0 prefetch (issued first: hides under Q-proj)
  const bf16* kb_g = ktg + (size_t)h * SP * DK;
  const bf16* vb_g = vtg + (size_t)h * DK * SP;
  const bf16* sp_ptr[6];
  int sp_str[6];
#pragma unroll
  for (int r = 0; r < 6; ++r) {
    int g = tid + 256 * r;
    if (g < 768) {                           // K granule
      int kb = g >> 8, n = (g >> 6) & 3, qd = (g >> 4) & 3, l5 = g & 15;
      sp_ptr[r] = kb_g + (size_t)(n * 16 + l5) * DK + kb * 32 + qd * 8;
      sp_str[r] = 64 * DK;
    } else {                                 // V granule
      int gv = g - 768, blk = gv >> 6;
      int kbv = blk / 6, n = blk % 6, qd = (gv >> 4) & 3, l5 = gv & 15;
      sp_ptr[r] = vb_g + (size_t)(n * 16 + l5) * SP + kbv * 32 + qd * 8;
      sp_str[r] = 64;
    }
  }
  bf16x8 kreg[6];
#pragma unroll
  for (int r = 0; r < 6; ++r) kreg[r] = *(const bf16x8*)sp_ptr[r];

  // ======== barrier-free Q^T projection (both tiles), z read DIRECT ========
  f32x4 qacc[2][6];
#pragma unroll
  for (int t2 = 0; t2 < 2; ++t2)
#pragma unroll
    for (int n = 0; n < 6; ++n) qacc[t2][n] = (f32x4){0.f, 0.f, 0.f, 0.f};
  const float* zc0 = &z[((size_t)b * D_ + quad * 8) * T_ + t0 + wv * 32 + l15];
  const float* wrow = &Wq[(size_t)(h * DK + l15) * D_ + quad * 8];
  for (int kb = 0; kb < 6; ++kb) {
    bf16x8 zf[2];
#pragma unroll
    for (int t2 = 0; t2 < 2; ++t2)
#pragma unroll
      for (int j = 0; j < 8; ++j)
        zf[t2][j] = (bf16)zc0[(size_t)(kb * 32 + j) * T_ + t2 * 16];
#pragma unroll
    for (int n = 0; n < 6; ++n) {
      const float* wp = wrow + (size_t)n * 16 * D_ + kb * 32;
      f32x4 wa = *(const f32x4*)wp, wb = *(const f32x4*)(wp + 4);
      bf16x8 wf;
#pragma unroll
      for (int u = 0; u < 4; ++u) { wf[u] = (bf16)wa[u]; wf[4 + u] = (bf16)wb[u]; }
      qacc[0][n] = __builtin_amdgcn_mfma_f32_16x16x32_bf16(wf, zf[0], qacc[0][n], 0, 0, 0);
      qacc[1][n] = __builtin_amdgcn_mfma_f32_16x16x32_bf16(wf, zf[1], qacc[1][n], 0, 0, 0);
    }
  }
  // scatter Q^T -> sigma-swizzled qt B-frags; rows = kbq*8 + wv*2 + t2
#pragma unroll
  for (int t2 = 0; t2 < 2; ++t2)
#pragma unroll
    for (int n = 0; n < 6; ++n) {
      f32x4 bq4 = *(const f32x4*)&bq[h * DK + n * 16 + quad * 4];
      int g = ((n & 1) * 2 + (quad >> 1)) * 16 + l15;
      int gs = g ^ ((g >> 3) & 7);
      bf16x4 pk;
#pragma unroll
      for (int r = 0; r < 4; ++r)
        pk[r] = (bf16)((qacc[t2][n][r] + bq4[r]) * (SCALE * LOG2E));
      *(bf16x4*)&qt[(size_t)(((n >> 1) * 8 + wv * 2 + t2) * 64 + gs) * 8 + (quad & 1) * 4] = pk;
    }
  bf16x8 qf[2][3];                           // Q^T fragments, same-wave read back
#pragma unroll
  for (int t2 = 0; t2 < 2; ++t2)
#pragma unroll
    for (int kb = 0; kb < 3; ++kb)
      qf[t2][kb] = *(const bf16x8*)&qt[(size_t)((kb * 8 + wv * 2 + t2) * 64 +
                                                (lane ^ ((lane >> 3) & 7))) * 8];

  f32x4 oaccT[2][6];
#pragma unroll
  for (int t2 = 0; t2 < 2; ++t2)
#pragma unroll
    for (int n = 0; n < 6; ++n) oaccT[t2][n] = (f32x4){0.f, 0.f, 0.f, 0.f};
  float m_run[2] = {-1e30f, -1e30f}, l_run[2] = {0.f, 0.f};

  for (int ch = 0; ch < 16; ++ch) {
    __syncthreads();                         // (A) prev readers (first: qt reads) done
#pragma unroll
    for (int r = 0; r < 6; ++r)              // regs -> LDS, lane-linear (conflict-free)
      *(bf16x8*)(smem + (size_t)(tid + 256 * r) * 16) = kreg[r];
    __syncthreads();                         // (B) staged
    if (ch < 15) {                           // issue next chunk's loads under compute
#pragma unroll
      for (int r = 0; r < 6; ++r) {
        sp_ptr[r] += sp_str[r];
        kreg[r] = *(const bf16x8*)sp_ptr[r];
      }
    }

    // ---- S^T = K·Q^T, kt frag reused across both t-tiles ----
    f32x4 scT[2][4];
#pragma unroll
    for (int t2 = 0; t2 < 2; ++t2)
#pragma unroll
      for (int n = 0; n < 4; ++n) scT[t2][n] = (f32x4){0.f, 0.f, 0.f, 0.f};
#pragma unroll
    for (int kb = 0; kb < 3; ++kb) {
#pragma unroll
      for (int n = 0; n < 4; ++n) {
        bf16x8 kf = *(const bf16x8*)&kt[(size_t)((kb * 4 + n) * 64 + lane) * 8];
        scT[0][n] = __builtin_amdgcn_mfma_f32_16x16x32_bf16(kf, qf[0][kb], scT[0][n], 0, 0, 0);
        scT[1][n] = __builtin_amdgcn_mfma_f32_16x16x32_bf16(kf, qf[1][kb], scT[1][n], 0, 0, 0);
      }
    }
    if (ch == 15) {                          // mask s >= 1000 (s-local >= 40)
#pragma unroll
      for (int t2 = 0; t2 < 2; ++t2)
#pragma unroll
        for (int r = 0; r < 4; ++r) {
          scT[t2][3][r] = -1e30f;
          if (quad >= 2) scT[t2][2][r] = -1e30f;
        }
    }

    // ---- per-tile softmax (tree + 2 shfls), defer-max, P^T -> sP both halves ----
    float mt[2];
#pragma unroll
    for (int t2 = 0; t2 < 2; ++t2) {
      float m8[8];
#pragma unroll
      for (int u = 0; u < 8; ++u)
        m8[u] = fmaxf(scT[t2][u >> 1][(u & 1) * 2], scT[t2][u >> 1][(u & 1) * 2 + 1]);
      float ma = fmaxf(fmaxf(m8[0], m8[1]), fmaxf(m8[2], m8[3]));
      float mb2 = fmaxf(fmaxf(m8[4], m8[5]), fmaxf(m8[6], m8[7]));
      float m0 = fmaxf(ma, mb2);
      m0 = fmaxf(m0, __shfl_xor(m0, 16, 64));
      m0 = fmaxf(m0, __shfl_xor(m0, 32, 64));
      mt[t2] = m0;
    }
    if (!__all(mt[0] - m_run[0] <= 8.f && mt[1] - m_run[1] <= 8.f)) {  // defer-max
#pragma unroll
      for (int t2 = 0; t2 < 2; ++t2) {
        float mn = fmaxf(m_run[t2], mt[t2]);
        float al = exp2f(m_run[t2] - mn);
        m_run[t2] = mn;
        l_run[t2] *= al;
#pragma unroll
        for (int n = 0; n < 6; ++n)
#pragma unroll
          for (int r = 0; r < 4; ++r) oaccT[t2][n][r] *= al;
      }
    }
#pragma unroll
    for (int t2 = 0; t2 < 2; ++t2) {
      float pr[4][4];
#pragma unroll
      for (int n = 0; n < 4; ++n)
#pragma unroll
        for (int r = 0; r < 4; ++r) pr[n][r] = exp2f(scT[t2][n][r] - m_run[t2]);
      float s8[8];
#pragma unroll
      for (int u = 0; u < 8; ++u)
        s8[u] = pr[u >> 1][(u & 1) * 2] + pr[u >> 1][(u & 1) * 2 + 1];
      float ls = ((s8[0] + s8[1]) + (s8[2] + s8[3])) + ((s8[4] + s8[5]) + (s8[6] + s8[7]));
      ls += __shfl_xor(ls, 16, 64);
      ls += __shfl_xor(ls, 32, 64);
      l_run[t2] += ls;
      // write both kb2 halves for this tile (packed b64, same-wave)
#pragma unroll
      for (int kb2 = 0; kb2 < 2; ++kb2)
#pragma unroll
        for (int nh = 0; nh < 2; ++nh) {
          int n = kb2 * 2 + nh;
          int g = (nh * 2 + (quad >> 1)) * 16 + l15;
          int gs = g ^ ((g >> 3) & 7);
          bf16x4 pk = {(bf16)pr[n][0], (bf16)pr[n][1], (bf16)pr[n][2], (bf16)pr[n][3]};
          *(bf16x4*)&sP[(size_t)(((wv * 2 + t2) * 2 + kb2) * 64 + gs) * 8 +
                        (quad & 1) * 4] = pk;
        }
    }

    // ---- PV: O^T += V·P^T, vt frag reused across both t-tiles ----
#pragma unroll
    for (int kb2 = 0; kb2 < 2; ++kb2) {
      bf16x8 pa[2];
#pragma unroll
      for (int t2 = 0; t2 < 2; ++t2)
        pa[t2] = *(const bf16x8*)&sP[(size_t)(((wv * 2 + t2) * 2 + kb2) * 64 +
                                              (lane ^ ((lane >> 3) & 7))) * 8];
#pragma unroll
      for (int n2 = 0; n2 < 6; ++n2) {
        bf16x8 vf = *(const bf16x8*)&vt[(size_t)((kb2 * 6 + n2) * 64 + lane) * 8];
        oaccT[0][n2] = __builtin_amdgcn_mfma_f32_16x16x32_bf16(vf, pa[0], oaccT[0][n2], 0, 0, 0);
        oaccT[1][n2] = __builtin_amdgcn_mfma_f32_16x16x32_bf16(vf, pa[1], oaccT[1][n2], 0, 0, 0);
      }
    }
  }

  // ---- epilogue: /l, direct bf16x4 global stores (no LDS, no barrier) ----
#pragma unroll
  for (int t2 = 0; t2 < 2; ++t2) {
    float inv = 1.0f / l_run[t2];
    bf16* orow = &owsT[((size_t)b * T_ + t0 + wv * 32 + t2 * 16 + l15) * D_ +
                       h * DK + quad * 4];
#pragma unroll
    for (int n2 = 0; n2 < 6; ++n2) {
      bf16x4 pk = {(bf16)(oaccT[t2][n2][0] * inv), (bf16)(oaccT[t2][n2][1] * inv),
                   (bf16)(oaccT[t2][n2][2] * inv), (bf16)(oaccT[t2][n2][3] * inv)};
      *(bf16x4*)&orow[n2 * 16] = pk;
    }
  }
}

extern "C" void kernel_launch(void* const* d_in, const int* in_sizes, int n_in,
                              void* d_out, int out_size, void* d_ws, size_t ws_size,
                              hipStream_t stream) {
  const float* z  = (const float*)d_in[0];
  const float* mb = (const float*)d_in[1];
  const float* Wq = (const float*)d_in[2];
  const float* bq = (const float*)d_in[3];
  const float* Wk = (const float*)d_in[4];
  const float* bk = (const float*)d_in[5];
  const float* Wv = (const float*)d_in[6];
  const float* bv = (const float*)d_in[7];
  const float* Wo = (const float*)d_in[8];
  const float* bo = (const float*)d_in[9];
  float* out = (float*)d_out;

  // ws: ktg | vtg | owsT (all bf16)
  bf16* ktg  = (bf16*)d_ws;
  bf16* vtg  = ktg + 2 * SP * DK;
  bf16* owsT = vtg + 2 * DK * SP;

  kv_kernel  <<<dim3(SP / 256, D_),    256, 0, stream>>>(mb, Wk, bk, Wv, bv, ktg, vtg);
  attn_kernel<<<dim3(T_ / 128, 2, B_), 256, 0, stream>>>(z, Wq, bq, ktg, vtg, owsT);
  proj_kernel<<<dim3(T_ / 256, 3, B_), 256, 0, stream>>>(owsT, Wo, bo, out);
}